// Round 21
// baseline (104.074 us; speedup 1.0000x reference)
//
#include <hip/hip_runtime.h>
#include <hip/hip_bf16.h>

typedef unsigned short ushort_t;
typedef __attribute__((ext_vector_type(8))) short short8;
typedef __attribute__((ext_vector_type(4))) float f32x4;
typedef __attribute__((ext_vector_type(8))) float f32x8;
typedef __attribute__((ext_vector_type(16))) float f32x16;

#define MFMA16(a, b, c) __builtin_amdgcn_mfma_f32_16x16x32_bf16((a), (b), (c), 0, 0, 0)
#define MFMA32(a, b, c) __builtin_amdgcn_mfma_f32_32x32x16_bf16((a), (b), (c), 0, 0, 0)

__device__ __forceinline__ ushort_t f2bf(float f) {
    return __builtin_bit_cast(ushort_t, __float2bfloat16(f));
}

#define CVTPK(lo, hi) ({ unsigned int r_; \
    asm("v_cvt_pk_bf16_f32 %0, %1, %2" : "=v"(r_) : "v"(lo), "v"(hi)); r_; })

// async global->LDS, 16B per lane (LDS dest = wave-uniform base + lane*16).
__device__ __forceinline__ void gl_lds16(const void* g, void* l) {
    __builtin_amdgcn_global_load_lds((const __attribute__((address_space(1))) void*)g,
                                     (__attribute__((address_space(3))) void*)l, 16, 0, 0);
}

// ---------------- Projections, one matrix per block; W^T built in-block in LDS.
// Blocks [0,512): x->Q.  [512,1024): y->K.  [1024,1536): y->VT (transposed).
__global__ __launch_bounds__(256) void proj3(
    const float* __restrict__ x, const float* __restrict__ y,
    const float* __restrict__ Wq, const float* __restrict__ bq,
    const float* __restrict__ Wk, const float* __restrict__ bk,
    const float* __restrict__ Wv, const float* __restrict__ bv,
    ushort_t* __restrict__ Qd, ushort_t* __restrict__ Kd, ushort_t* __restrict__ VTd,
    float qscale)
{
    __shared__ __align__(16) char smem[65536];

    const int t = threadIdx.x;
    const int mat = blockIdx.x >> 9;          // 0=Q, 1=K, 2=V
    const int pb  = blockIdx.x & 511;
    const float* src = (mat == 0) ? x : y;
    const float* W   = (mat == 0) ? Wq : (mat == 1) ? Wk : Wv;
    const float* bb  = (mat == 0) ? bq : (mat == 1) ? bk : bv;
    const float  sc  = (mat == 0) ? qscale : 1.0f;

    const int w  = t >> 6;
    const int l  = t & 63;
    const int lg = l >> 4;
    const int ln = l & 15;
    const int acol = lg * 8;

    {
        const char* srcb = (const char*)(src + (size_t)(pb * 64) * 128);
        #pragma unroll
        for (int i = 0; i < 8; ++i) {
            int off = i * 4096 + w * 1024 + l * 16;
            int soff = off ^ (((off >> 9) & 7) << 4);
            gl_lds16(srcb + soff, smem + i * 4096 + w * 1024);
        }
    }

    char* wt = smem + 32768;
    #pragma unroll
    for (int i = 0; i < 16; ++i) {
        int idx = t + i * 256;
        int k  = idx >> 5;
        int c0 = (idx & 31) * 4;
        f32x4 v = ((const f32x4*)W)[idx];
        #pragma unroll
        for (int j = 0; j < 4; ++j) {
            int c = c0 + j;
            int byte = (c * 256 + k * 2) ^ ((c & 7) << 4);
            *(ushort_t*)(wt + byte) = f2bf(v[j]);
        }
    }
    __syncthreads();

    short8 afrag[4];
    {
        const int row = w * 16 + ln;
        const int sw = (row & 7) << 4;
        #pragma unroll
        for (int kc = 0; kc < 4; ++kc) {
            int off0 = row * 512 + lg * 32 + kc * 128;
            f32x4 a0 = *(const f32x4*)(smem + (off0 ^ sw));
            f32x4 a1 = *(const f32x4*)(smem + ((off0 + 16) ^ sw));
            short8 a;
            #pragma unroll
            for (int j = 0; j < 4; ++j) { a[j] = (short)f2bf(a0[j]); a[4 + j] = (short)f2bf(a1[j]); }
            afrag[kc] = a;
        }
    }
    __syncthreads();

    if (mat < 2) {
        ushort_t* tile = (ushort_t*)smem;     // [64][144]
        #pragma unroll
        for (int ct = 0; ct < 8; ++ct) {
            f32x4 acc = {0.f, 0.f, 0.f, 0.f};
            const int c = ct * 16 + ln;
            #pragma unroll
            for (int kc = 0; kc < 4; ++kc) {
                int byte = (c * 256 + (kc * 32 + acol) * 2) ^ ((c & 7) << 4);
                short8 bfr = *(const short8*)(wt + byte);
                acc = MFMA16(afrag[kc], bfr, acc);
            }
            float bvv = bb[c];
            #pragma unroll
            for (int reg = 0; reg < 4; ++reg)
                tile[(w * 16 + lg * 4 + reg) * 144 + c] = f2bf((acc[reg] + bvv) * sc);
        }
        __syncthreads();
        const int row = t >> 2, ch = t & 3;
        ushort_t* dst1 = (mat == 0 ? Qd : Kd) + (size_t)(pb * 64 + row) * 128 + ch * 32;
        #pragma unroll
        for (int j = 0; j < 4; ++j)
            *(short8*)(dst1 + j * 8) = *(const short8*)&tile[row * 144 + ch * 32 + j * 8];
    } else {
        ushort_t* vt = (ushort_t*)smem;       // [128*64] swizzled
        #pragma unroll
        for (int ct = 0; ct < 8; ++ct) {
            f32x4 acc = {0.f, 0.f, 0.f, 0.f};
            const int c = ct * 16 + ln;
            #pragma unroll
            for (int kc = 0; kc < 4; ++kc) {
                int byte = (c * 256 + (kc * 32 + acol) * 2) ^ ((c & 7) << 4);
                short8 bfr = *(const short8*)(wt + byte);
                acc = MFMA16(afrag[kc], bfr, acc);
            }
            float bvv = bb[c];
            #pragma unroll
            for (int reg = 0; reg < 4; ++reg) {
                int rloc = w * 16 + lg * 4 + reg;
                int byte = (c * 128 + rloc * 2) ^ ((c & 7) << 4);
                *(ushort_t*)((char*)vt + byte) = f2bf(acc[reg] + bvv);
            }
        }
        __syncthreads();
        const int r0b = pb * 64;
        const int b   = r0b >> 11;
        const int kv0 = r0b & 2047;
        const int c    = t >> 1;
        const int half = t & 1;
        ushort_t* dst = VTd + (size_t)b * 128 * 2048 + (size_t)c * 2048 + kv0 + half * 32;
        #pragma unroll
        for (int j = 0; j < 4; ++j) {
            int byte = (c * 128 + (half * 32 + j * 8) * 2) ^ ((c & 7) << 4);
            *(short8*)(dst + j * 8) = *(const short8*)((const char*)vt + byte);
        }
    }
}

// ---------------- Flash attention: 64 q/block, 4 waves = 2 q-groups x 2 kv-halves.
// 2-stage software pipeline (r18) + split QK accumulator chains (4-deep instead
// of 8-deep) + 8-reg deferred row-sum. 4-slot dbuf, one vmcnt(0)+barrier per tile.
#define KVBLK 64
#define NT (2048 / KVBLK)

#define PACK2(S, A, OUTF) {                                          \
    unsigned u0 = CVTPK(S[(A)*8+0], S[(A)*8+1]);                     \
    unsigned u1 = CVTPK(S[(A)*8+2], S[(A)*8+3]);                     \
    unsigned u2 = CVTPK(S[(A)*8+4], S[(A)*8+5]);                     \
    unsigned u3 = CVTPK(S[(A)*8+6], S[(A)*8+7]);                     \
    asm("v_permlane32_swap_b32 %0, %1" : "+v"(u0), "+v"(u2));        \
    asm("v_permlane32_swap_b32 %0, %1" : "+v"(u1), "+v"(u3));        \
    union { unsigned wds[4]; short8 s8; } f_;                        \
    f_.wds[0] = u0; f_.wds[1] = u1; f_.wds[2] = u2; f_.wds[3] = u3;  \
    OUTF = f_.s8;                                                    \
}

// One pipeline step: process tile T (exp2/pack/PV from SINA+SINB/VFIN),
// QK(T+1) into split accumulators SOUTA/SOUTB, V(T+1)->VFOUT, stage T+2.
#define STEP(T, SINA, SINB, VFIN, SOUTA, SOUTB, VFOUT)                       \
  {                                                                          \
    const int ktn_ = ((T) + 2 < NT) ? (T) + 2 : 0;                           \
    asm volatile("s_waitcnt vmcnt(0)" ::: "memory");                         \
    __builtin_amdgcn_s_barrier();                                            \
    char* stb_ = smem_ + (((T) & 1) * 32768);                                \
    stageK(stb_, ktn_);                                                      \
    stageV(stb_ + 16384, ktn_);                                              \
    const char* nb_ = smem_ + ((((T) + 1) & 1) * 32768);                     \
    _Pragma("unroll")                                                        \
    for (int i = 0; i < 16; ++i) { SOUTA[i] = 0.f; SOUTB[i] = 0.f; }         \
    __builtin_amdgcn_s_setprio(1);                                           \
    _Pragma("unroll")                                                        \
    for (int kc = 0; kc < 4; ++kc) {                                         \
        int colA_ = (h * 16 + kc * 32) ^ ksw;                                \
        short8 kfA_ = *(const short8*)(nb_ + krow * 256 + colA_);            \
        SOUTA = MFMA32(kfA_, qfrag[kc], SOUTA);                              \
        int colB_ = (h * 16 + (kc + 4) * 32) ^ ksw;                          \
        short8 kfB_ = *(const short8*)(nb_ + krow * 256 + colB_);            \
        SOUTB = MFMA32(kfB_, qfrag[kc + 4], SOUTB);                          \
    }                                                                        \
    __builtin_amdgcn_s_setprio(0);                                           \
    _Pragma("unroll")                                                        \
    for (int i = 0; i < 16; ++i) SINA[i] = __builtin_exp2f(SINA[i] + SINB[i]); \
    _Pragma("unroll")                                                        \
    for (int i = 0; i < 8; ++i) ls[i] += SINA[i] + SINA[i + 8];              \
    short8 pf0_, pf1_;                                                       \
    PACK2(SINA, 0, pf0_);                                                    \
    PACK2(SINA, 1, pf1_);                                                    \
    __builtin_amdgcn_s_setprio(1);                                           \
    _Pragma("unroll")                                                        \
    for (int db = 0; db < 4; ++db) {                                         \
        o[db] = MFMA32(VFIN[db * 2 + 0], pf0_, o[db]);                       \
        o[db] = MFMA32(VFIN[db * 2 + 1], pf1_, o[db]);                       \
    }                                                                        \
    __builtin_amdgcn_s_setprio(0);                                           \
    _Pragma("unroll")                                                        \
    for (int db = 0; db < 4; ++db) {                                         \
        int d_ = db * 32 + lq;                                               \
        int vrow_ = d_ >> 1;                                                 \
        int vsw_ = (vrow_ & 15) << 4;                                        \
        _Pragma("unroll")                                                    \
        for (int ks = 0; ks < 2; ++ks) {                                     \
            int colb_ = ((d_ & 1) << 7) | (kvh * 64 + ks * 32 + h * 16);     \
            VFOUT[db * 2 + ks] =                                             \
                *(const short8*)(nb_ + 16384 + vrow_ * 256 + (colb_ ^ vsw_));\
        }                                                                    \
    }                                                                        \
  }

__global__ __launch_bounds__(256, 2) void attn_kernel(
    const ushort_t* __restrict__ Q, const ushort_t* __restrict__ K,
    const ushort_t* __restrict__ VT, float* __restrict__ out)
{
    __shared__ __align__(16) char smem_[65536];   // [K0|V0|K1|V1] 16 KB each

    const int t = threadIdx.x;
    const int bid = (int)blockIdx.x;
    const int wg = (bid & 7) * 64 + (bid >> 3);   // XCD swizzle (512 % 8 == 0)
    const int b  = wg >> 5;
    const int q0blk = (wg & 31) * 64;

    const char* Kb  = (const char*)(K  + (size_t)b * 2048 * 128);
    const char* VTb = (const char*)(VT + (size_t)b * 128 * 2048);
    const ushort_t* Qb = Q + (size_t)b * 2048 * 128;

    const int w   = t >> 6;
    const int qg  = w >> 1;
    const int kvh = w & 1;
    const int l  = t & 63;
    const int lq = l & 31;
    const int h  = l >> 5;
    const int q0 = q0blk + qg * 32;

    short8 qfrag[8];
    {
        const ushort_t* qp = Qb + (size_t)(q0 + lq) * 128 + h * 8;
        #pragma unroll
        for (int kc = 0; kc < 8; ++kc)
            qfrag[kc] = *(const short8*)(qp + kc * 16);
    }

    f32x16 o[4];
    #pragma unroll
    for (int db = 0; db < 4; ++db)
        #pragma unroll
        for (int i = 0; i < 16; ++i) o[db][i] = 0.f;
    f32x8 ls;
    #pragma unroll
    for (int i = 0; i < 8; ++i) ls[i] = 0.f;

    auto stageK = [&](char* kd, int kt) {
        const char* kb = Kb + (size_t)kt * KVBLK * 256;
        #pragma unroll
        for (int i = 0; i < 4; ++i) {
            int base = w * 4096 + i * 1024;
            int p = base + l * 16;
            int pl = p ^ (((p >> 8) & 15) << 4);
            gl_lds16(kb + pl, kd + base);
        }
    };
    auto stageV = [&](char* vd, int kt) {
        const int kv2 = kt * KVBLK * 2;
        #pragma unroll
        for (int i = 0; i < 4; ++i) {
            int base = w * 4096 + i * 1024;
            int p = base + l * 16;
            int pl = p ^ (((p >> 8) & 15) << 4);
            int dv = ((pl >> 8) << 1) | ((pl >> 7) & 1);
            gl_lds16(VTb + (size_t)dv * 4096 + kv2 + (pl & 127), vd + base);
        }
    };

    const int krow = kvh * 32 + lq;
    const int ksw = (krow & 15) << 4;

    f32x16 sA1, sA2, sB1, sB2;
    short8 vfA[8], vfB[8];

    // ---- prologue: stage 0; QK(0)->sA1/sA2 (split chains); V(0)->vfA; stage 1 in flight
    stageK(smem_, 0);
    stageV(smem_ + 16384, 0);
    asm volatile("s_waitcnt vmcnt(0)" ::: "memory");
    __builtin_amdgcn_s_barrier();
    stageK(smem_ + 32768, 1);
    stageV(smem_ + 49152, 1);

    #pragma unroll
    for (int i = 0; i < 16; ++i) { sA1[i] = 0.f; sA2[i] = 0.f; }
    __builtin_amdgcn_s_setprio(1);
    #pragma unroll
    for (int kc = 0; kc < 4; ++kc) {
        int colA = (h * 16 + kc * 32) ^ ksw;
        short8 kfA = *(const short8*)(smem_ + krow * 256 + colA);
        sA1 = MFMA32(kfA, qfrag[kc], sA1);
        int colB = (h * 16 + (kc + 4) * 32) ^ ksw;
        short8 kfB = *(const short8*)(smem_ + krow * 256 + colB);
        sA2 = MFMA32(kfB, qfrag[kc + 4], sA2);
    }
    __builtin_amdgcn_s_setprio(0);
    #pragma unroll
    for (int db = 0; db < 4; ++db) {
        int d = db * 32 + lq;
        int vrow = d >> 1;
        int vsw = (vrow & 15) << 4;
        #pragma unroll
        for (int ks = 0; ks < 2; ++ks) {
            int colb = ((d & 1) << 7) | (kvh * 64 + ks * 32 + h * 16);
            vfA[db * 2 + ks] = *(const short8*)(smem_ + 16384 + vrow * 256 + (colb ^ vsw));
        }
    }

    // ---- main loop: 2 tiles per iteration, static register parity
    for (int tt = 0; tt < NT; tt += 2) {
        STEP(tt,     sA1, sA2, vfA, sB1, sB2, vfB);
        STEP(tt + 1, sB1, sB2, vfB, sA1, sA2, vfA);
    }

    asm volatile("s_waitcnt vmcnt(0)" ::: "memory");  // drain dummy stages before overlay

    // ---- fold deferred row-sum
    float lsum;
    {
        float a4[4];
        #pragma unroll
        for (int i = 0; i < 4; ++i) a4[i] = ls[i] + ls[i + 4];
        lsum = (a4[0] + a4[1]) + (a4[2] + a4[3]);
    }
    lsum += __shfl_xor(lsum, 32);

    // ---- merge kv-halves (plain add), then store
    __syncthreads();
    float* mrg = (float*)smem_;
    const int mo = qg * 4224 + lq * 132;
    const int mlb = 8448;

    if (kvh == 1) {
        #pragma unroll
        for (int db = 0; db < 4; ++db) {
            #pragma unroll
            for (int rq = 0; rq < 4; ++rq) {
                f32x4 v4;
                #pragma unroll
                for (int j = 0; j < 4; ++j) v4[j] = o[db][rq * 4 + j];
                *(f32x4*)&mrg[mo + db * 32 + rq * 8 + 4 * h] = v4;
            }
        }
        if (h == 0) mrg[mlb + qg * 64 + lq] = lsum;
    }
    __syncthreads();
    if (kvh == 0) {
        float inv = 1.0f / (lsum + mrg[mlb + qg * 64 + lq]);
        float* ob = out + (size_t)b * 2048 * 128 + (size_t)(q0 + lq) * 128;
        #pragma unroll
        for (int db = 0; db < 4; ++db) {
            #pragma unroll
            for (int rq = 0; rq < 4; ++rq) {
                f32x4 p4v = *(const f32x4*)&mrg[mo + db * 32 + rq * 8 + 4 * h];
                f32x4 st;
                #pragma unroll
                for (int j = 0; j < 4; ++j)
                    st[j] = (o[db][rq * 4 + j] + p4v[j]) * inv;
                *(f32x4*)(ob + db * 32 + rq * 8 + 4 * h) = st;
            }
        }
    }
}

extern "C" void kernel_launch(void* const* d_in, const int* in_sizes, int n_in,
                              void* d_out, int out_size, void* d_ws, size_t ws_size,
                              hipStream_t stream) {
    (void)in_sizes; (void)n_in; (void)out_size; (void)ws_size;
    const float* x  = (const float*)d_in[0];
    const float* y  = (const float*)d_in[1];
    const float* Wq = (const float*)d_in[2];
    const float* bq = (const float*)d_in[3];
    const float* Wk = (const float*)d_in[4];
    const float* bk = (const float*)d_in[5];
    const float* Wv = (const float*)d_in[6];
    const float* bv = (const float*)d_in[7];
    float* out = (float*)d_out;

    ushort_t* qws  = (ushort_t*)d_ws;
    ushort_t* kws  = qws + (size_t)32768 * 128;
    ushort_t* vtws = kws + (size_t)32768 * 128;

    // 1/sqrt(128) * log2(e): softmax computed in exp2 domain
    const float qscale = (float)(1.4426950408889634 / 11.313708498984761);

    proj3<<<1536, 256, 0, stream>>>(x, y, Wq, bq, Wk, bk, Wv, bv, qws, kws, vtws, qscale);
    attn_kernel<<<512, 256, 0, stream>>>(qws, kws, vtws, out);
}

// Round 22
// 92.341 us; speedup vs baseline: 1.1271x; 1.1271x over previous
//
#include <hip/hip_runtime.h>
#include <hip/hip_bf16.h>

typedef unsigned short ushort_t;
typedef __attribute__((ext_vector_type(8))) short short8;
typedef __attribute__((ext_vector_type(4))) float f32x4;
typedef __attribute__((ext_vector_type(16))) float f32x16;

#define MFMA16(a, b, c) __builtin_amdgcn_mfma_f32_16x16x32_bf16((a), (b), (c), 0, 0, 0)
#define MFMA32(a, b, c) __builtin_amdgcn_mfma_f32_32x32x16_bf16((a), (b), (c), 0, 0, 0)

__device__ __forceinline__ ushort_t f2bf(float f) {
    return __builtin_bit_cast(ushort_t, __float2bfloat16(f));
}

#define CVTPK(lo, hi) ({ unsigned int r_; \
    asm("v_cvt_pk_bf16_f32 %0, %1, %2" : "=v"(r_) : "v"(lo), "v"(hi)); r_; })

// async global->LDS, 16B per lane (LDS dest = wave-uniform base + lane*16).
__device__ __forceinline__ void gl_lds16(const void* g, void* l) {
    __builtin_amdgcn_global_load_lds((const __attribute__((address_space(1))) void*)g,
                                     (__attribute__((address_space(3))) void*)l, 16, 0, 0);
}

// ---------------- Projections, one matrix per block; W^T built in-block in LDS.
// Blocks [0,512): x->Q.  [512,1024): y->K.  [1024,1536): y->VT (transposed).
__global__ __launch_bounds__(256) void proj3(
    const float* __restrict__ x, const float* __restrict__ y,
    const float* __restrict__ Wq, const float* __restrict__ bq,
    const float* __restrict__ Wk, const float* __restrict__ bk,
    const float* __restrict__ Wv, const float* __restrict__ bv,
    ushort_t* __restrict__ Qd, ushort_t* __restrict__ Kd, ushort_t* __restrict__ VTd,
    float qscale)
{
    __shared__ __align__(16) char smem[65536];

    const int t = threadIdx.x;
    const int mat = blockIdx.x >> 9;          // 0=Q, 1=K, 2=V
    const int pb  = blockIdx.x & 511;
    const float* src = (mat == 0) ? x : y;
    const float* W   = (mat == 0) ? Wq : (mat == 1) ? Wk : Wv;
    const float* bb  = (mat == 0) ? bq : (mat == 1) ? bk : bv;
    const float  sc  = (mat == 0) ? qscale : 1.0f;

    const int w  = t >> 6;
    const int l  = t & 63;
    const int lg = l >> 4;
    const int ln = l & 15;
    const int acol = lg * 8;

    {
        const char* srcb = (const char*)(src + (size_t)(pb * 64) * 128);
        #pragma unroll
        for (int i = 0; i < 8; ++i) {
            int off = i * 4096 + w * 1024 + l * 16;
            int soff = off ^ (((off >> 9) & 7) << 4);
            gl_lds16(srcb + soff, smem + i * 4096 + w * 1024);
        }
    }

    char* wt = smem + 32768;
    #pragma unroll
    for (int i = 0; i < 16; ++i) {
        int idx = t + i * 256;
        int k  = idx >> 5;
        int c0 = (idx & 31) * 4;
        f32x4 v = ((const f32x4*)W)[idx];
        #pragma unroll
        for (int j = 0; j < 4; ++j) {
            int c = c0 + j;
            int byte = (c * 256 + k * 2) ^ ((c & 7) << 4);
            *(ushort_t*)(wt + byte) = f2bf(v[j]);
        }
    }
    __syncthreads();

    short8 afrag[4];
    {
        const int row = w * 16 + ln;
        const int sw = (row & 7) << 4;
        #pragma unroll
        for (int kc = 0; kc < 4; ++kc) {
            int off0 = row * 512 + lg * 32 + kc * 128;
            f32x4 a0 = *(const f32x4*)(smem + (off0 ^ sw));
            f32x4 a1 = *(const f32x4*)(smem + ((off0 + 16) ^ sw));
            short8 a;
            #pragma unroll
            for (int j = 0; j < 4; ++j) { a[j] = (short)f2bf(a0[j]); a[4 + j] = (short)f2bf(a1[j]); }
            afrag[kc] = a;
        }
    }
    __syncthreads();

    if (mat < 2) {
        ushort_t* tile = (ushort_t*)smem;     // [64][144]
        #pragma unroll
        for (int ct = 0; ct < 8; ++ct) {
            f32x4 acc = {0.f, 0.f, 0.f, 0.f};
            const int c = ct * 16 + ln;
            #pragma unroll
            for (int kc = 0; kc < 4; ++kc) {
                int byte = (c * 256 + (kc * 32 + acol) * 2) ^ ((c & 7) << 4);
                short8 bfr = *(const short8*)(wt + byte);
                acc = MFMA16(afrag[kc], bfr, acc);
            }
            float bvv = bb[c];
            #pragma unroll
            for (int reg = 0; reg < 4; ++reg)
                tile[(w * 16 + lg * 4 + reg) * 144 + c] = f2bf((acc[reg] + bvv) * sc);
        }
        __syncthreads();
        const int row = t >> 2, ch = t & 3;
        ushort_t* dst1 = (mat == 0 ? Qd : Kd) + (size_t)(pb * 64 + row) * 128 + ch * 32;
        #pragma unroll
        for (int j = 0; j < 4; ++j)
            *(short8*)(dst1 + j * 8) = *(const short8*)&tile[row * 144 + ch * 32 + j * 8];
    } else {
        ushort_t* vt = (ushort_t*)smem;       // [128*64] swizzled
        #pragma unroll
        for (int ct = 0; ct < 8; ++ct) {
            f32x4 acc = {0.f, 0.f, 0.f, 0.f};
            const int c = ct * 16 + ln;
            #pragma unroll
            for (int kc = 0; kc < 4; ++kc) {
                int byte = (c * 256 + (kc * 32 + acol) * 2) ^ ((c & 7) << 4);
                short8 bfr = *(const short8*)(wt + byte);
                acc = MFMA16(afrag[kc], bfr, acc);
            }
            float bvv = bb[c];
            #pragma unroll
            for (int reg = 0; reg < 4; ++reg) {
                int rloc = w * 16 + lg * 4 + reg;
                int byte = (c * 128 + rloc * 2) ^ ((c & 7) << 4);
                *(ushort_t*)((char*)vt + byte) = f2bf(acc[reg] + bvv);
            }
        }
        __syncthreads();
        const int r0b = pb * 64;
        const int b   = r0b >> 11;
        const int kv0 = r0b & 2047;
        const int c    = t >> 1;
        const int half = t & 1;
        ushort_t* dst = VTd + (size_t)b * 128 * 2048 + (size_t)c * 2048 + kv0 + half * 32;
        #pragma unroll
        for (int j = 0; j < 4; ++j) {
            int byte = (c * 128 + (half * 32 + j * 8) * 2) ^ ((c & 7) << 4);
            *(short8*)(dst + j * 8) = *(const short8*)((const char*)vt + byte);
        }
    }
}

// ---------------- Flash attention: 64 q/block, 4 waves = 2 q-groups x 2 kv-halves.
// 2-stage software pipeline: per step, QK(t+1) [LDS+MFMA] || exp2/pack(t) [VALU]
// || PV(t) [reg-MFMA] || V(t+1)->regs [LDS] are independent streams.
// 4-slot dbuf, one vmcnt(0)+barrier per tile. No-max exp2 softmax.
#define KVBLK 64
#define NT (2048 / KVBLK)

#define PACK2(S, A, OUTF) {                                          \
    unsigned u0 = CVTPK(S[(A)*8+0], S[(A)*8+1]);                     \
    unsigned u1 = CVTPK(S[(A)*8+2], S[(A)*8+3]);                     \
    unsigned u2 = CVTPK(S[(A)*8+4], S[(A)*8+5]);                     \
    unsigned u3 = CVTPK(S[(A)*8+6], S[(A)*8+7]);                     \
    asm("v_permlane32_swap_b32 %0, %1" : "+v"(u0), "+v"(u2));        \
    asm("v_permlane32_swap_b32 %0, %1" : "+v"(u1), "+v"(u3));        \
    union { unsigned wds[4]; short8 s8; } f_;                        \
    f_.wds[0] = u0; f_.wds[1] = u1; f_.wds[2] = u2; f_.wds[3] = u3;  \
    OUTF = f_.s8;                                                    \
}

// One pipeline step: process tile T (pack+PV from SIN/VFIN), QK(T+1)->SOUT,
// V(T+1)->VFOUT, stage tiles T+2 into buf(T&1).
#define STEP(T, SIN, VFIN, SOUT, VFOUT)                                      \
  {                                                                          \
    const int ktn_ = ((T) + 2 < NT) ? (T) + 2 : 0;                           \
    asm volatile("s_waitcnt vmcnt(0)" ::: "memory");                         \
    __builtin_amdgcn_s_barrier();                                            \
    char* stb_ = smem_ + (((T) & 1) * 32768);                                \
    stageK(stb_, ktn_);                                                      \
    stageV(stb_ + 16384, ktn_);                                              \
    const char* nb_ = smem_ + ((((T) + 1) & 1) * 32768);                     \
    _Pragma("unroll")                                                        \
    for (int i = 0; i < 16; ++i) SOUT[i] = 0.f;                              \
    __builtin_amdgcn_s_setprio(1);                                           \
    _Pragma("unroll")                                                        \
    for (int kc = 0; kc < 8; ++kc) {                                         \
        int col_ = (h * 16 + kc * 32) ^ ksw;                                 \
        short8 kf_ = *(const short8*)(nb_ + krow * 256 + col_);              \
        SOUT = MFMA32(kf_, qfrag[kc], SOUT);                                 \
    }                                                                        \
    __builtin_amdgcn_s_setprio(0);                                           \
    _Pragma("unroll")                                                        \
    for (int i = 0; i < 16; ++i) SIN[i] = __builtin_exp2f(SIN[i]);           \
    _Pragma("unroll")                                                        \
    for (int i = 0; i < 16; ++i) ls[i] += SIN[i];                            \
    short8 pf0_, pf1_;                                                       \
    PACK2(SIN, 0, pf0_);                                                     \
    PACK2(SIN, 1, pf1_);                                                     \
    __builtin_amdgcn_s_setprio(1);                                           \
    _Pragma("unroll")                                                        \
    for (int db = 0; db < 4; ++db) {                                         \
        o[db] = MFMA32(VFIN[db * 2 + 0], pf0_, o[db]);                       \
        o[db] = MFMA32(VFIN[db * 2 + 1], pf1_, o[db]);                       \
    }                                                                        \
    __builtin_amdgcn_s_setprio(0);                                           \
    _Pragma("unroll")                                                        \
    for (int db = 0; db < 4; ++db) {                                         \
        int d_ = db * 32 + lq;                                               \
        int vrow_ = d_ >> 1;                                                 \
        int vsw_ = (vrow_ & 15) << 4;                                        \
        _Pragma("unroll")                                                    \
        for (int ks = 0; ks < 2; ++ks) {                                     \
            int colb_ = ((d_ & 1) << 7) | (kvh * 64 + ks * 32 + h * 16);     \
            VFOUT[db * 2 + ks] =                                             \
                *(const short8*)(nb_ + 16384 + vrow_ * 256 + (colb_ ^ vsw_));\
        }                                                                    \
    }                                                                        \
  }

__global__ __launch_bounds__(256, 2) void attn_kernel(
    const ushort_t* __restrict__ Q, const ushort_t* __restrict__ K,
    const ushort_t* __restrict__ VT, float* __restrict__ out)
{
    __shared__ __align__(16) char smem_[65536];   // [K0|V0|K1|V1] 16 KB each

    const int t = threadIdx.x;
    const int bid = (int)blockIdx.x;
    const int wg = (bid & 7) * 64 + (bid >> 3);   // XCD swizzle (512 % 8 == 0)
    const int b  = wg >> 5;
    const int q0blk = (wg & 31) * 64;

    const char* Kb  = (const char*)(K  + (size_t)b * 2048 * 128);
    const char* VTb = (const char*)(VT + (size_t)b * 128 * 2048);
    const ushort_t* Qb = Q + (size_t)b * 2048 * 128;

    const int w   = t >> 6;
    const int qg  = w >> 1;
    const int kvh = w & 1;
    const int l  = t & 63;
    const int lq = l & 31;
    const int h  = l >> 5;
    const int q0 = q0blk + qg * 32;

    short8 qfrag[8];
    {
        const ushort_t* qp = Qb + (size_t)(q0 + lq) * 128 + h * 8;
        #pragma unroll
        for (int kc = 0; kc < 8; ++kc)
            qfrag[kc] = *(const short8*)(qp + kc * 16);
    }

    f32x16 o[4];
    #pragma unroll
    for (int db = 0; db < 4; ++db)
        #pragma unroll
        for (int i = 0; i < 16; ++i) o[db][i] = 0.f;
    f32x16 ls;
    #pragma unroll
    for (int i = 0; i < 16; ++i) ls[i] = 0.f;

    auto stageK = [&](char* kd, int kt) {
        const char* kb = Kb + (size_t)kt * KVBLK * 256;
        #pragma unroll
        for (int i = 0; i < 4; ++i) {
            int base = w * 4096 + i * 1024;
            int p = base + l * 16;
            int pl = p ^ (((p >> 8) & 15) << 4);
            gl_lds16(kb + pl, kd + base);
        }
    };
    auto stageV = [&](char* vd, int kt) {
        const int kv2 = kt * KVBLK * 2;
        #pragma unroll
        for (int i = 0; i < 4; ++i) {
            int base = w * 4096 + i * 1024;
            int p = base + l * 16;
            int pl = p ^ (((p >> 8) & 15) << 4);
            int dv = ((pl >> 8) << 1) | ((pl >> 7) & 1);
            gl_lds16(VTb + (size_t)dv * 4096 + kv2 + (pl & 127), vd + base);
        }
    };

    const int krow = kvh * 32 + lq;
    const int ksw = (krow & 15) << 4;

    f32x16 sA, sB;
    short8 vfA[8], vfB[8];

    // ---- prologue: stage 0; QK(0)->sA; V(0)->vfA; stage 1 in flight
    stageK(smem_, 0);
    stageV(smem_ + 16384, 0);
    asm volatile("s_waitcnt vmcnt(0)" ::: "memory");
    __builtin_amdgcn_s_barrier();
    stageK(smem_ + 32768, 1);
    stageV(smem_ + 49152, 1);

    #pragma unroll
    for (int i = 0; i < 16; ++i) sA[i] = 0.f;
    __builtin_amdgcn_s_setprio(1);
    #pragma unroll
    for (int kc = 0; kc < 8; ++kc) {
        int col = (h * 16 + kc * 32) ^ ksw;
        short8 kf = *(const short8*)(smem_ + krow * 256 + col);
        sA = MFMA32(kf, qfrag[kc], sA);
    }
    __builtin_amdgcn_s_setprio(0);
    #pragma unroll
    for (int db = 0; db < 4; ++db) {
        int d = db * 32 + lq;
        int vrow = d >> 1;
        int vsw = (vrow & 15) << 4;
        #pragma unroll
        for (int ks = 0; ks < 2; ++ks) {
            int colb = ((d & 1) << 7) | (kvh * 64 + ks * 32 + h * 16);
            vfA[db * 2 + ks] = *(const short8*)(smem_ + 16384 + vrow * 256 + (colb ^ vsw));
        }
    }

    // ---- main loop: 2 tiles per iteration, static register parity
    for (int tt = 0; tt < NT; tt += 2) {
        STEP(tt,     sA, vfA, sB, vfB);
        STEP(tt + 1, sB, vfB, sA, vfA);
    }

    asm volatile("s_waitcnt vmcnt(0)" ::: "memory");  // drain dummy stages before overlay

    // ---- fold deferred row-sum
    float lsum;
    {
        float a8[8];
        #pragma unroll
        for (int i = 0; i < 8; ++i) a8[i] = ls[i] + ls[i + 8];
        #pragma unroll
        for (int i = 0; i < 4; ++i) a8[i] += a8[i + 4];
        lsum = (a8[0] + a8[1]) + (a8[2] + a8[3]);
    }
    lsum += __shfl_xor(lsum, 32);

    // ---- merge kv-halves (plain add), then store
    __syncthreads();
    float* mrg = (float*)smem_;
    const int mo = qg * 4224 + lq * 132;
    const int mlb = 8448;

    if (kvh == 1) {
        #pragma unroll
        for (int db = 0; db < 4; ++db) {
            #pragma unroll
            for (int rq = 0; rq < 4; ++rq) {
                f32x4 v4;
                #pragma unroll
                for (int j = 0; j < 4; ++j) v4[j] = o[db][rq * 4 + j];
                *(f32x4*)&mrg[mo + db * 32 + rq * 8 + 4 * h] = v4;
            }
        }
        if (h == 0) mrg[mlb + qg * 64 + lq] = lsum;
    }
    __syncthreads();
    if (kvh == 0) {
        float inv = 1.0f / (lsum + mrg[mlb + qg * 64 + lq]);
        float* ob = out + (size_t)b * 2048 * 128 + (size_t)(q0 + lq) * 128;
        #pragma unroll
        for (int db = 0; db < 4; ++db) {
            #pragma unroll
            for (int rq = 0; rq < 4; ++rq) {
                f32x4 p4v = *(const f32x4*)&mrg[mo + db * 32 + rq * 8 + 4 * h];
                f32x4 st;
                #pragma unroll
                for (int j = 0; j < 4; ++j)
                    st[j] = (o[db][rq * 4 + j] + p4v[j]) * inv;
                *(f32x4*)(ob + db * 32 + rq * 8 + 4 * h) = st;
            }
        }
    }
}

extern "C" void kernel_launch(void* const* d_in, const int* in_sizes, int n_in,
                              void* d_out, int out_size, void* d_ws, size_t ws_size,
                              hipStream_t stream) {
    (void)in_sizes; (void)n_in; (void)out_size; (void)ws_size;
    const float* x  = (const float*)d_in[0];
    const float* y  = (const float*)d_in[1];
    const float* Wq = (const float*)d_in[2];
    const float* bq = (const float*)d_in[3];
    const float* Wk = (const float*)d_in[4];
    const float* bk = (const float*)d_in[5];
    const float* Wv = (const float*)d_in[6];
    const float* bv = (const float*)d_in[7];
    float* out = (float*)d_out;

    ushort_t* qws  = (ushort_t*)d_ws;
    ushort_t* kws  = qws + (size_t)32768 * 128;
    ushort_t* vtws = kws + (size_t)32768 * 128;

    // 1/sqrt(128) * log2(e): softmax computed in exp2 domain
    const float qscale = (float)(1.4426950408889634 / 11.313708498984761);

    proj3<<<1536, 256, 0, stream>>>(x, y, Wq, bq, Wk, bk, Wv, bv, qws, kws, vtws, qscale);
    attn_kernel<<<512, 256, 0, stream>>>(qws, kws, vtws, out);
}

// Round 23
// 92.128 us; speedup vs baseline: 1.1297x; 1.0023x over previous
//
#include <hip/hip_runtime.h>
#include <hip/hip_bf16.h>

typedef unsigned short ushort_t;
typedef __attribute__((ext_vector_type(8))) short short8;
typedef __attribute__((ext_vector_type(4))) float f32x4;
typedef __attribute__((ext_vector_type(16))) float f32x16;

#define MFMA16(a, b, c) __builtin_amdgcn_mfma_f32_16x16x32_bf16((a), (b), (c), 0, 0, 0)
#define MFMA32(a, b, c) __builtin_amdgcn_mfma_f32_32x32x16_bf16((a), (b), (c), 0, 0, 0)

__device__ __forceinline__ ushort_t f2bf(float f) {
    return __builtin_bit_cast(ushort_t, __float2bfloat16(f));
}

#define CVTPK(lo, hi) ({ unsigned int r_; \
    asm("v_cvt_pk_bf16_f32 %0, %1, %2" : "=v"(r_) : "v"(lo), "v"(hi)); r_; })

// async global->LDS, 16B per lane (LDS dest = wave-uniform base + lane*16).
__device__ __forceinline__ void gl_lds16(const void* g, void* l) {
    __builtin_amdgcn_global_load_lds((const __attribute__((address_space(1))) void*)g,
                                     (__attribute__((address_space(3))) void*)l, 16, 0, 0);
}

// ---------------- Projections, one matrix per block; W^T built in-block in LDS.
// Blocks [0,512): x->Q.  [512,1024): y->K.  [1024,1536): y->VT (transposed).
__global__ __launch_bounds__(256) void proj3(
    const float* __restrict__ x, const float* __restrict__ y,
    const float* __restrict__ Wq, const float* __restrict__ bq,
    const float* __restrict__ Wk, const float* __restrict__ bk,
    const float* __restrict__ Wv, const float* __restrict__ bv,
    ushort_t* __restrict__ Qd, ushort_t* __restrict__ Kd, ushort_t* __restrict__ VTd,
    float qscale)
{
    __shared__ __align__(16) char smem[65536];

    const int t = threadIdx.x;
    const int mat = blockIdx.x >> 9;          // 0=Q, 1=K, 2=V
    const int pb  = blockIdx.x & 511;
    const float* src = (mat == 0) ? x : y;
    const float* W   = (mat == 0) ? Wq : (mat == 1) ? Wk : Wv;
    const float* bb  = (mat == 0) ? bq : (mat == 1) ? bk : bv;
    const float  sc  = (mat == 0) ? qscale : 1.0f;

    const int w  = t >> 6;
    const int l  = t & 63;
    const int lg = l >> 4;
    const int ln = l & 15;
    const int acol = lg * 8;

    {
        const char* srcb = (const char*)(src + (size_t)(pb * 64) * 128);
        #pragma unroll
        for (int i = 0; i < 8; ++i) {
            int off = i * 4096 + w * 1024 + l * 16;
            int soff = off ^ (((off >> 9) & 7) << 4);
            gl_lds16(srcb + soff, smem + i * 4096 + w * 1024);
        }
    }

    char* wt = smem + 32768;
    #pragma unroll
    for (int i = 0; i < 16; ++i) {
        int idx = t + i * 256;
        int k  = idx >> 5;
        int c0 = (idx & 31) * 4;
        f32x4 v = ((const f32x4*)W)[idx];
        #pragma unroll
        for (int j = 0; j < 4; ++j) {
            int c = c0 + j;
            int byte = (c * 256 + k * 2) ^ ((c & 7) << 4);
            *(ushort_t*)(wt + byte) = f2bf(v[j]);
        }
    }
    __syncthreads();

    short8 afrag[4];
    {
        const int row = w * 16 + ln;
        const int sw = (row & 7) << 4;
        #pragma unroll
        for (int kc = 0; kc < 4; ++kc) {
            int off0 = row * 512 + lg * 32 + kc * 128;
            f32x4 a0 = *(const f32x4*)(smem + (off0 ^ sw));
            f32x4 a1 = *(const f32x4*)(smem + ((off0 + 16) ^ sw));
            short8 a;
            #pragma unroll
            for (int j = 0; j < 4; ++j) { a[j] = (short)f2bf(a0[j]); a[4 + j] = (short)f2bf(a1[j]); }
            afrag[kc] = a;
        }
    }
    __syncthreads();

    if (mat < 2) {
        ushort_t* tile = (ushort_t*)smem;     // [64][144]
        #pragma unroll
        for (int ct = 0; ct < 8; ++ct) {
            f32x4 acc = {0.f, 0.f, 0.f, 0.f};
            const int c = ct * 16 + ln;
            #pragma unroll
            for (int kc = 0; kc < 4; ++kc) {
                int byte = (c * 256 + (kc * 32 + acol) * 2) ^ ((c & 7) << 4);
                short8 bfr = *(const short8*)(wt + byte);
                acc = MFMA16(afrag[kc], bfr, acc);
            }
            float bvv = bb[c];
            #pragma unroll
            for (int reg = 0; reg < 4; ++reg)
                tile[(w * 16 + lg * 4 + reg) * 144 + c] = f2bf((acc[reg] + bvv) * sc);
        }
        __syncthreads();
        const int row = t >> 2, ch = t & 3;
        ushort_t* dst1 = (mat == 0 ? Qd : Kd) + (size_t)(pb * 64 + row) * 128 + ch * 32;
        #pragma unroll
        for (int j = 0; j < 4; ++j)
            *(short8*)(dst1 + j * 8) = *(const short8*)&tile[row * 144 + ch * 32 + j * 8];
    } else {
        ushort_t* vt = (ushort_t*)smem;       // [128*64] swizzled
        #pragma unroll
        for (int ct = 0; ct < 8; ++ct) {
            f32x4 acc = {0.f, 0.f, 0.f, 0.f};
            const int c = ct * 16 + ln;
            #pragma unroll
            for (int kc = 0; kc < 4; ++kc) {
                int byte = (c * 256 + (kc * 32 + acol) * 2) ^ ((c & 7) << 4);
                short8 bfr = *(const short8*)(wt + byte);
                acc = MFMA16(afrag[kc], bfr, acc);
            }
            float bvv = bb[c];
            #pragma unroll
            for (int reg = 0; reg < 4; ++reg) {
                int rloc = w * 16 + lg * 4 + reg;
                int byte = (c * 128 + rloc * 2) ^ ((c & 7) << 4);
                *(ushort_t*)((char*)vt + byte) = f2bf(acc[reg] + bvv);
            }
        }
        __syncthreads();
        const int r0b = pb * 64;
        const int b   = r0b >> 11;
        const int kv0 = r0b & 2047;
        const int c    = t >> 1;
        const int half = t & 1;
        ushort_t* dst = VTd + (size_t)b * 128 * 2048 + (size_t)c * 2048 + kv0 + half * 32;
        #pragma unroll
        for (int j = 0; j < 4; ++j) {
            int byte = (c * 128 + (half * 32 + j * 8) * 2) ^ ((c & 7) << 4);
            *(short8*)(dst + j * 8) = *(const short8*)((const char*)vt + byte);
        }
    }
}

// ---------------- Flash attention: 64 q/block, 4 waves = 2 q-groups x 2 kv-halves.
// 2-stage software pipeline: per step, QK(t+1) [LDS+MFMA] || exp2/pack(t) [VALU]
// || PV(t) [reg-MFMA] || V(t+1)->regs [LDS] are independent streams.
// 4-slot dbuf, one vmcnt(0)+barrier per tile. No-max exp2 softmax.
#define KVBLK 64
#define NT (2048 / KVBLK)

#define PACK2(S, A, OUTF) {                                          \
    unsigned u0 = CVTPK(S[(A)*8+0], S[(A)*8+1]);                     \
    unsigned u1 = CVTPK(S[(A)*8+2], S[(A)*8+3]);                     \
    unsigned u2 = CVTPK(S[(A)*8+4], S[(A)*8+5]);                     \
    unsigned u3 = CVTPK(S[(A)*8+6], S[(A)*8+7]);                     \
    asm("v_permlane32_swap_b32 %0, %1" : "+v"(u0), "+v"(u2));        \
    asm("v_permlane32_swap_b32 %0, %1" : "+v"(u1), "+v"(u3));        \
    union { unsigned wds[4]; short8 s8; } f_;                        \
    f_.wds[0] = u0; f_.wds[1] = u1; f_.wds[2] = u2; f_.wds[3] = u3;  \
    OUTF = f_.s8;                                                    \
}

// One pipeline step: process tile T (pack+PV from SIN/VFIN), QK(T+1)->SOUT,
// V(T+1)->VFOUT, stage tiles T+2 into buf(T&1).
#define STEP(T, SIN, VFIN, SOUT, VFOUT)                                      \
  {                                                                          \
    const int ktn_ = ((T) + 2 < NT) ? (T) + 2 : 0;                           \
    asm volatile("s_waitcnt vmcnt(0)" ::: "memory");                         \
    __builtin_amdgcn_s_barrier();                                            \
    char* stb_ = smem_ + (((T) & 1) * 32768);                                \
    stageK(stb_, ktn_);                                                      \
    stageV(stb_ + 16384, ktn_);                                              \
    const char* nb_ = smem_ + ((((T) + 1) & 1) * 32768);                     \
    _Pragma("unroll")                                                        \
    for (int i = 0; i < 16; ++i) SOUT[i] = 0.f;                              \
    __builtin_amdgcn_s_setprio(1);                                           \
    _Pragma("unroll")                                                        \
    for (int kc = 0; kc < 8; ++kc) {                                         \
        int col_ = (h * 16 + kc * 32) ^ ksw;                                 \
        short8 kf_ = *(const short8*)(nb_ + krow * 256 + col_);              \
        SOUT = MFMA32(kf_, qfrag[kc], SOUT);                                 \
    }                                                                        \
    __builtin_amdgcn_s_setprio(0);                                           \
    _Pragma("unroll")                                                        \
    for (int i = 0; i < 16; ++i) SIN[i] = __builtin_exp2f(SIN[i]);           \
    _Pragma("unroll")                                                        \
    for (int i = 0; i < 16; ++i) ls[i] += SIN[i];                            \
    short8 pf0_, pf1_;                                                       \
    PACK2(SIN, 0, pf0_);                                                     \
    PACK2(SIN, 1, pf1_);                                                     \
    __builtin_amdgcn_s_setprio(1);                                           \
    _Pragma("unroll")                                                        \
    for (int db = 0; db < 4; ++db) {                                         \
        o[db] = MFMA32(VFIN[db * 2 + 0], pf0_, o[db]);                       \
        o[db] = MFMA32(VFIN[db * 2 + 1], pf1_, o[db]);                       \
    }                                                                        \
    __builtin_amdgcn_s_setprio(0);                                           \
    _Pragma("unroll")                                                        \
    for (int db = 0; db < 4; ++db) {                                         \
        int d_ = db * 32 + lq;                                               \
        int vrow_ = d_ >> 1;                                                 \
        int vsw_ = (vrow_ & 15) << 4;                                        \
        _Pragma("unroll")                                                    \
        for (int ks = 0; ks < 2; ++ks) {                                     \
            int colb_ = ((d_ & 1) << 7) | (kvh * 64 + ks * 32 + h * 16);     \
            VFOUT[db * 2 + ks] =                                             \
                *(const short8*)(nb_ + 16384 + vrow_ * 256 + (colb_ ^ vsw_));\
        }                                                                    \
    }                                                                        \
  }

__global__ __launch_bounds__(256, 2) void attn_kernel(
    const ushort_t* __restrict__ Q, const ushort_t* __restrict__ K,
    const ushort_t* __restrict__ VT, float* __restrict__ out)
{
    __shared__ __align__(16) char smem_[65536];   // [K0|V0|K1|V1] 16 KB each

    const int t = threadIdx.x;
    const int bid = (int)blockIdx.x;
    const int wg = (bid & 7) * 64 + (bid >> 3);   // XCD swizzle (512 % 8 == 0)
    const int b  = wg >> 5;
    const int q0blk = (wg & 31) * 64;

    const char* Kb  = (const char*)(K  + (size_t)b * 2048 * 128);
    const char* VTb = (const char*)(VT + (size_t)b * 128 * 2048);
    const ushort_t* Qb = Q + (size_t)b * 2048 * 128;

    const int w   = t >> 6;
    const int qg  = w >> 1;
    const int kvh = w & 1;
    const int l  = t & 63;
    const int lq = l & 31;
    const int h  = l >> 5;
    const int q0 = q0blk + qg * 32;

    short8 qfrag[8];
    {
        const ushort_t* qp = Qb + (size_t)(q0 + lq) * 128 + h * 8;
        #pragma unroll
        for (int kc = 0; kc < 8; ++kc)
            qfrag[kc] = *(const short8*)(qp + kc * 16);
    }

    f32x16 o[4];
    #pragma unroll
    for (int db = 0; db < 4; ++db)
        #pragma unroll
        for (int i = 0; i < 16; ++i) o[db][i] = 0.f;
    f32x16 ls;
    #pragma unroll
    for (int i = 0; i < 16; ++i) ls[i] = 0.f;

    auto stageK = [&](char* kd, int kt) {
        const char* kb = Kb + (size_t)kt * KVBLK * 256;
        #pragma unroll
        for (int i = 0; i < 4; ++i) {
            int base = w * 4096 + i * 1024;
            int p = base + l * 16;
            int pl = p ^ (((p >> 8) & 15) << 4);
            gl_lds16(kb + pl, kd + base);
        }
    };
    auto stageV = [&](char* vd, int kt) {
        const int kv2 = kt * KVBLK * 2;
        #pragma unroll
        for (int i = 0; i < 4; ++i) {
            int base = w * 4096 + i * 1024;
            int p = base + l * 16;
            int pl = p ^ (((p >> 8) & 15) << 4);
            int dv = ((pl >> 8) << 1) | ((pl >> 7) & 1);
            gl_lds16(VTb + (size_t)dv * 4096 + kv2 + (pl & 127), vd + base);
        }
    };

    const int krow = kvh * 32 + lq;
    const int ksw = (krow & 15) << 4;

    f32x16 sA, sB;
    short8 vfA[8], vfB[8];

    // ---- prologue: stage 0; QK(0)->sA; V(0)->vfA; stage 1 in flight
    stageK(smem_, 0);
    stageV(smem_ + 16384, 0);
    asm volatile("s_waitcnt vmcnt(0)" ::: "memory");
    __builtin_amdgcn_s_barrier();
    stageK(smem_ + 32768, 1);
    stageV(smem_ + 49152, 1);

    #pragma unroll
    for (int i = 0; i < 16; ++i) sA[i] = 0.f;
    __builtin_amdgcn_s_setprio(1);
    #pragma unroll
    for (int kc = 0; kc < 8; ++kc) {
        int col = (h * 16 + kc * 32) ^ ksw;
        short8 kf = *(const short8*)(smem_ + krow * 256 + col);
        sA = MFMA32(kf, qfrag[kc], sA);
    }
    __builtin_amdgcn_s_setprio(0);
    #pragma unroll
    for (int db = 0; db < 4; ++db) {
        int d = db * 32 + lq;
        int vrow = d >> 1;
        int vsw = (vrow & 15) << 4;
        #pragma unroll
        for (int ks = 0; ks < 2; ++ks) {
            int colb = ((d & 1) << 7) | (kvh * 64 + ks * 32 + h * 16);
            vfA[db * 2 + ks] = *(const short8*)(smem_ + 16384 + vrow * 256 + (colb ^ vsw));
        }
    }

    // ---- main loop: 2 tiles per iteration, static register parity
    for (int tt = 0; tt < NT; tt += 2) {
        STEP(tt,     sA, vfA, sB, vfB);
        STEP(tt + 1, sB, vfB, sA, vfA);
    }

    asm volatile("s_waitcnt vmcnt(0)" ::: "memory");  // drain dummy stages before overlay

    // ---- fold deferred row-sum
    float lsum;
    {
        float a8[8];
        #pragma unroll
        for (int i = 0; i < 8; ++i) a8[i] = ls[i] + ls[i + 8];
        #pragma unroll
        for (int i = 0; i < 4; ++i) a8[i] += a8[i + 4];
        lsum = (a8[0] + a8[1]) + (a8[2] + a8[3]);
    }
    lsum += __shfl_xor(lsum, 32);

    // ---- merge kv-halves (plain add), then store
    __syncthreads();
    float* mrg = (float*)smem_;
    const int mo = qg * 4224 + lq * 132;
    const int mlb = 8448;

    if (kvh == 1) {
        #pragma unroll
        for (int db = 0; db < 4; ++db) {
            #pragma unroll
            for (int rq = 0; rq < 4; ++rq) {
                f32x4 v4;
                #pragma unroll
                for (int j = 0; j < 4; ++j) v4[j] = o[db][rq * 4 + j];
                *(f32x4*)&mrg[mo + db * 32 + rq * 8 + 4 * h] = v4;
            }
        }
        if (h == 0) mrg[mlb + qg * 64 + lq] = lsum;
    }
    __syncthreads();
    if (kvh == 0) {
        float inv = 1.0f / (lsum + mrg[mlb + qg * 64 + lq]);
        float* ob = out + (size_t)b * 2048 * 128 + (size_t)(q0 + lq) * 128;
        #pragma unroll
        for (int db = 0; db < 4; ++db) {
            #pragma unroll
            for (int rq = 0; rq < 4; ++rq) {
                f32x4 p4v = *(const f32x4*)&mrg[mo + db * 32 + rq * 8 + 4 * h];
                f32x4 st;
                #pragma unroll
                for (int j = 0; j < 4; ++j)
                    st[j] = (o[db][rq * 4 + j] + p4v[j]) * inv;
                *(f32x4*)(ob + db * 32 + rq * 8 + 4 * h) = st;
            }
        }
    }
}

extern "C" void kernel_launch(void* const* d_in, const int* in_sizes, int n_in,
                              void* d_out, int out_size, void* d_ws, size_t ws_size,
                              hipStream_t stream) {
    (void)in_sizes; (void)n_in; (void)out_size; (void)ws_size;
    const float* x  = (const float*)d_in[0];
    const float* y  = (const float*)d_in[1];
    const float* Wq = (const float*)d_in[2];
    const float* bq = (const float*)d_in[3];
    const float* Wk = (const float*)d_in[4];
    const float* bk = (const float*)d_in[5];
    const float* Wv = (const float*)d_in[6];
    const float* bv = (const float*)d_in[7];
    float* out = (float*)d_out;

    ushort_t* qws  = (ushort_t*)d_ws;
    ushort_t* kws  = qws + (size_t)32768 * 128;
    ushort_t* vtws = kws + (size_t)32768 * 128;

    // 1/sqrt(128) * log2(e): softmax computed in exp2 domain
    const float qscale = (float)(1.4426950408889634 / 11.313708498984761);

    proj3<<<1536, 256, 0, stream>>>(x, y, Wq, bq, Wk, bk, Wv, bv, qws, kws, vtws, qscale);
    attn_kernel<<<512, 256, 0, stream>>>(qws, kws, vtws, out);
}